// Round 14
// baseline (202.801 us; speedup 1.0000x reference)
//
#include <hip/hip_runtime.h>

// Problem constants (B=2, T=2048, C=1024, H=16, hd=64)
#define T_SEQ 2048
#define NH    16
#define HD    64
#define CDIM  1024
#define BDIM  2

using floatx4 = __attribute__((ext_vector_type(4))) float;
using bf16x8  = __attribute__((ext_vector_type(8))) __bf16;
using half4   = __attribute__((ext_vector_type(4))) _Float16;
using half8   = __attribute__((ext_vector_type(8))) _Float16;
typedef unsigned short u16;

__device__ __forceinline__ u16 f2bf(float f) {
  unsigned int u = __float_as_uint(f);
  u += 0x7fffu + ((u >> 16) & 1u);          // RNE
  return (u16)(u >> 16);
}
__device__ __forceinline__ float bf2f(u16 h) {
  return __uint_as_float(((unsigned int)h) << 16);
}
__device__ __forceinline__ u16 f2h(float f) {
  union { _Float16 h; u16 u; } c; c.h = (_Float16)f; return c.u;
}
// pack two f32 -> one u32 of 2 f16 (RNE, via scalar cvts; compiler fuses pack)
__device__ __forceinline__ unsigned pkh_rne(float a, float b) {
  return (unsigned)f2h(a) | ((unsigned)f2h(b) << 16);
}
// packed f32x2 -> f16x2 (RTZ)
__device__ __forceinline__ unsigned pk2h(float a, float b) {
  return __builtin_bit_cast(unsigned, __builtin_amdgcn_cvt_pkrtz(a, b));
}
// async global->LDS, 16B/lane; LDS dest must be wave-uniform base + lane*16.
__device__ __forceinline__ void gld16(const void* g, const void* l) {
  __builtin_amdgcn_global_load_lds(
      (const __attribute__((address_space(1))) unsigned int*)(unsigned long long)g,
      (__attribute__((address_space(3))) unsigned int*)(unsigned int)(unsigned long long)l,
      16, 0, 0);
}
// 2D XCD tiling: 8 XCDs = 4 row-groups x 2 col-groups (proven -5.7us in R8).
__device__ __forceinline__ void xcd_tile2d(int& row0, int& col0) {
  const int bid = blockIdx.y * gridDim.x + blockIdx.x;
  const int x = bid & 7, l = bid >> 3;
  const int rg = x >> 1, cg = x & 1;
  row0 = (rg * 8 + (l & 7)) * 128;
  col0 = (cg * (gridDim.y >> 1) + (l >> 3)) * 128;
}

// ---------------- fused preprocessing: x cast + weight transposes + trig table --------
// q/k sections of wqT get a per-head PAIR PERMUTATION: new row j holds old
// feature 2j (j<32) / 2(j-32)+1 (j>=32), making RoPE lane-local in the gemm
// epilogue. 2048x32 (t,i)->(cos,sin) table (512KB, L2-resident) replaces trig.
__global__ __launch_bounds__(256) void preproc(const float* __restrict__ x,
                                               const float* __restrict__ w_qkv,
                                               const float* __restrict__ w_out,
                                               u16* __restrict__ xb,
                                               u16* __restrict__ wqT,
                                               u16* __restrict__ woT,
                                               float2* __restrict__ tab) {
  __shared__ float tile[32][33];
  int blk = blockIdx.x, tid = threadIdx.x;
  if (blk >= 8192) {                        // trig table: 64K entries (t,i)
    int idx = (blk - 8192) * 256 + tid;
    int t = idx >> 5, i = idx & 31;
    float inv_rev = exp2f(-0.4152410118609203f * (float)i) * 0.15915494309189535f;
    float rev = (float)t * inv_rev;
    float fr  = rev - floorf(rev);
    tab[idx] = make_float2(__builtin_amdgcn_cosf(fr), __builtin_amdgcn_sinf(fr));
    return;
  }
  if (blk < 4096) {                         // cast x -> bf16 (4M floats, float4 per thread)
    int i = blk * 256 + tid;
    float4 v = ((const float4*)x)[i];
    ushort4 o;
    o.x = f2bf(v.x); o.y = f2bf(v.y); o.z = f2bf(v.z); o.w = f2bf(v.w);
    ((ushort4*)xb)[i] = o;
    return;
  }
  const float* W; u16* WT; int K, N, bx, by;
  if (blk < 4096 + 3072) {                  // w_qkv (1024,3072) -> wqT (3072,1024)
    int idx = blk - 4096; W = w_qkv; WT = wqT; K = 1024; N = 3072;
    bx = idx % 96; by = idx / 96;
  } else {                                  // w_out (1024,1024) -> woT
    int idx = blk - 7168; W = w_out; WT = woT; K = 1024; N = 1024;
    bx = idx & 31; by = idx >> 5;
  }
  int n0 = bx * 32, k0 = by * 32;
  int tx = tid & 31, ty = tid >> 5;         // (32,8)
#pragma unroll
  for (int i = 0; i < 32; i += 8)
    tile[ty + i][tx] = W[(size_t)(k0 + ty + i) * N + n0 + tx];
  __syncthreads();
#pragma unroll
  for (int i = 0; i < 32; i += 8) {
    int n = n0 + ty + i;
    int dest = n;
    if (N == 3072 && n < 2048) {            // q,k: pair-permute within each head
      int f = n & 63;
      dest = (n & ~63) | ((f >> 1) + ((f & 1) << 5));
    }
    WT[(size_t)dest * K + k0 + tx] = f2bf(tile[tx][ty + i]);
  }
}

// ---------------- QKV GEMM with fused RoPE + V-pack epilogue ----------
// R14: 2-TILE-DEEP prefetch (3-buffer rotation, vmcnt(8)). The R10 form was
// 1-deep: vmcnt(4) waited on loads issued one barrier earlier, exposing
// (load latency - one ~300cy compute phase) every tile. Now tile ki+2 is
// issued while computing ki; two compute phases + two barriers cover each
// load (T4: steady-state N = 4 loads/tile x 2 tiles in flight = 8).
// Race-free: buffer written at ki is buf[(ki+2)%3] == buf[(ki-1)%3], whose
// readers finished before this iteration's top barrier. LDS 48KB -> still
// 3 blocks/CU (grid-limited).
__global__ __launch_bounds__(256) void gemm_qkv_fused(const u16* __restrict__ A,
                                                      const u16* __restrict__ BT,
                                                      const float2* __restrict__ tab,
                                                      u16* __restrict__ qf16,
                                                      u16* __restrict__ kf16,
                                                      float* __restrict__ kt_out,
                                                      float* __restrict__ vt_out,
                                                      u16* __restrict__ vtf) {
  __shared__ u16 smem[6][128 * 32];         // [0..2]=A rot3, [3..5]=B rot3; reused for V^T
  const int K = 1024;
  const int tid  = threadIdx.x;
  const int lane = tid & 63, wave = tid >> 6;
  const int quad = lane >> 4, l16 = lane & 15;
  const int wm = (wave & 1) * 64, wn = (wave >> 1) * 64;
  int row0, col0;
  xcd_tile2d(row0, col0);
  const int srow = tid >> 2;
  const int sc   = tid & 3;
  const int sgc  = (sc ^ ((srow >> 1) & 3)) * 8;
  floatx4 acc[4][4] = {};

  auto stage = [&](int buf, int k0) {
    gld16(A  + (size_t)(row0 + srow     ) * K + k0 + sgc, &smem[buf][srow * 32 + sc * 8]);
    gld16(A  + (size_t)(row0 + srow + 64) * K + k0 + sgc, &smem[buf][(srow + 64) * 32 + sc * 8]);
    gld16(BT + (size_t)(col0 + srow     ) * K + k0 + sgc, &smem[3 + buf][srow * 32 + sc * 8]);
    gld16(BT + (size_t)(col0 + srow + 64) * K + k0 + sgc, &smem[3 + buf][(srow + 64) * 32 + sc * 8]);
  };

  const int nk = K >> 5;
  stage(0, 0);
  stage(1, 32);
  for (int ki = 0; ki < nk; ki++) {
    const int cur = ki % 3;
    __builtin_amdgcn_s_barrier();           // all waves done reading buf (ki-1)%3
    int kn = ki + 2 < nk ? ki + 2 : nk - 1; // clamp: tail re-stages (harmless)
    stage((ki + 2) % 3, kn << 5);
    asm volatile("s_waitcnt vmcnt(8)" ::: "memory");  // tile ki landed; 8 in flight
    __builtin_amdgcn_s_barrier();           // whole tile ki visible to all waves
    bf16x8 af[4], bfv[4];
#pragma unroll
    for (int mt = 0; mt < 4; mt++) {
      int r = wm + mt * 16 + l16;
      af[mt] = *(const bf16x8*)&smem[cur][r * 32 + (quad ^ ((r >> 1) & 3)) * 8];
    }
#pragma unroll
    for (int nt = 0; nt < 4; nt++) {
      int r = wn + nt * 16 + l16;
      bfv[nt] = *(const bf16x8*)&smem[3 + cur][r * 32 + (quad ^ ((r >> 1) & 3)) * 8];
    }
#pragma unroll
    for (int mt = 0; mt < 4; mt++)
#pragma unroll
      for (int nt = 0; nt < 4; nt++)
        acc[mt][nt] = __builtin_amdgcn_mfma_f32_16x16x32_bf16(af[mt], bfv[nt], acc[mt][nt], 0, 0, 0);
  }
  asm volatile("s_waitcnt vmcnt(0)" ::: "memory");  // drain tail stages

  // ---- fused epilogue ----
  const int sec = col0 >> 10;               // 0=q, 1=k, 2=v
  const int h   = ((col0 & 1023) + wn) >> 6;  // wave's 64 cols = one head
  const int b   = row0 >> 11;               // whole block within one batch
  const int tbase = (row0 & 2047) + wm;     // wave's token base
  const size_t hb = (size_t)(b * NH + h) * T_SEQ;

  if (sec < 2) {
    // RoPE (lane-local): x1=acc[mt][no], x2=acc[mt][no+2]. d'-interleaved
    // store: one dword holds (o1(i), o2(i)) at u16 index rb + 2i.
    const float S = 0.18033688011112042f;   // 0.125 * log2(e): base-2 softmax
#pragma unroll
    for (int mt = 0; mt < 4; mt++)
#pragma unroll
      for (int r = 0; r < 4; r++) {
        int t = tbase + mt * 16 + quad * 4 + r;
        size_t rb = (hb + t) * 64;
#pragma unroll
        for (int no = 0; no < 2; no++) {
          int i = no * 16 + l16;
          float2 cn = tab[t * 32 + i];
          float x1 = acc[mt][no][r], x2 = acc[mt][no + 2][r];
          float o1 = x1 * cn.x - x2 * cn.y;
          float o2 = x1 * cn.y + x2 * cn.x;
          if (sec == 0) {
            *(unsigned*)&qf16[rb + 2 * i] = pkh_rne(o1 * S, o2 * S);
          } else {
            *(unsigned*)&kf16[rb + 2 * i] = pkh_rne(o1, o2);
            kt_out[rb + i]      = o1;       // canonical layout (checked output)
            kt_out[rb + i + 32] = o2;
          }
        }
      }
  } else {
    // V: vt_out fp32 direct (coalesced), vtf (BH,64,T) f16 via LDS transpose.
#pragma unroll
    for (int mt = 0; mt < 4; mt++)
#pragma unroll
      for (int nt = 0; nt < 4; nt++)
#pragma unroll
        for (int r = 0; r < 4; r++) {
          int t = tbase + mt * 16 + quad * 4 + r;
          vt_out[(hb + t) * 64 + nt * 16 + l16] = acc[mt][nt][r];
        }
    __syncthreads();                        // all waves done with staging LDS
    u16* tb = &smem[0][0] + wave * 2432;    // per-wave scratch (32 x stride-72)
#pragma unroll
    for (int p = 0; p < 2; p++) {           // two 32-d passes (fits LDS)
#pragma unroll
      for (int mt = 0; mt < 4; mt++)
#pragma unroll
        for (int ntl = 0; ntl < 2; ntl++) {
          int dl = ntl * 16 + l16;          // d within pass
          // pack 4 rows (r=0..3, consecutive rowr) into one ds_write_b64
          half4 hv;
          hv[0] = (_Float16)acc[mt][p * 2 + ntl][0];
          hv[1] = (_Float16)acc[mt][p * 2 + ntl][1];
          hv[2] = (_Float16)acc[mt][p * 2 + ntl][2];
          hv[3] = (_Float16)acc[mt][p * 2 + ntl][3];
          *(half4*)&tb[dl * 72 + mt * 16 + quad * 4] = hv;
        }
      // same-wave write->read on same pointer: compiler orders via lgkmcnt
#pragma unroll
      for (int it = 0; it < 8; it++) {
        int dl = it * 4 + quad;
        int d  = p * 32 + dl;
        ushort4 vv = *(const ushort4*)&tb[dl * 72 + l16 * 4];
        *(ushort4*)&vtf[((size_t)(b * NH + h) * 64 + d) * T_SEQ + tbase + l16 * 4] = vv;
      }
      __syncthreads();                      // pass isolation across waves sharing smem
    }
  }
}

// ---------------- output-projection GEMM: 128x64 tiles (proven R9) ----------
// Keeps dbuf + counted vmcnt: proven at low occupancy (R2, 1-2 blocks/CU).
__global__ __launch_bounds__(256) void gemm_out(const u16* __restrict__ A,
                                                const u16* __restrict__ BT,
                                                float* __restrict__ Cf) {
  __shared__ u16 As[2][128 * 32];
  __shared__ u16 Bs[2][64 * 32];
  const int K = 1024, N = 1024;
  const int tid  = threadIdx.x;
  const int lane = tid & 63, wave = tid >> 6;
  const int quad = lane >> 4, l16 = lane & 15;
  const int wm = (wave & 1) * 64, wn = (wave >> 1) * 32;
  const int bid = blockIdx.y * gridDim.x + blockIdx.x;   // grid (32,16)
  const int xx = bid & 7, l = bid >> 3;                  // l in 0..63
  const int row0 = ((xx >> 1) * 8 + (l & 7)) * 128;      // 32 row-tiles
  const int col0 = ((xx & 1) * 8 + (l >> 3)) * 64;       // 16 col-tiles (64 wide)
  const int srow = tid >> 2;
  const int sc   = tid & 3;
  const int sgc  = (sc ^ ((srow >> 1) & 3)) * 8;
  floatx4 acc[4][2] = {};

  auto stage = [&](int buf, int k0) {
    gld16(A  + (size_t)(row0 + srow     ) * K + k0 + sgc, &As[buf][srow * 32 + sc * 8]);
    gld16(A  + (size_t)(row0 + srow + 64) * K + k0 + sgc, &As[buf][(srow + 64) * 32 + sc * 8]);
    gld16(BT + (size_t)(col0 + srow     ) * K + k0 + sgc, &Bs[buf][srow * 32 + sc * 8]);
  };

  const int nk = K >> 5;
  stage(0, 0);
  for (int ki = 0; ki < nk; ki++) {
    const int cur = ki & 1;
    __builtin_amdgcn_s_barrier();
    int kn = ki + 1 < nk ? ki + 1 : nk - 1;
    stage(cur ^ 1, kn << 5);
    asm volatile("s_waitcnt vmcnt(3)" ::: "memory");  // tile ki landed; 3 in flight
    __builtin_amdgcn_s_barrier();
    bf16x8 af[4], bfv[2];
#pragma unroll
    for (int mt = 0; mt < 4; mt++) {
      int r = wm + mt * 16 + l16;
      af[mt] = *(const bf16x8*)&As[cur][r * 32 + (quad ^ ((r >> 1) & 3)) * 8];
    }
#pragma unroll
    for (int nt = 0; nt < 2; nt++) {
      int r = wn + nt * 16 + l16;
      bfv[nt] = *(const bf16x8*)&Bs[cur][r * 32 + (quad ^ ((r >> 1) & 3)) * 8];
    }
#pragma unroll
    for (int mt = 0; mt < 4; mt++)
#pragma unroll
      for (int nt = 0; nt < 2; nt++)
        acc[mt][nt] = __builtin_amdgcn_mfma_f32_16x16x32_bf16(af[mt], bfv[nt], acc[mt][nt], 0, 0, 0);
  }
  asm volatile("s_waitcnt vmcnt(0)" ::: "memory");
#pragma unroll
  for (int mt = 0; mt < 4; mt++)
#pragma unroll
    for (int nt = 0; nt < 2; nt++)
#pragma unroll
      for (int r = 0; r < 4; r++) {
        int row = row0 + wm + mt * 16 + quad * 4 + r;
        int col = col0 + wn + nt * 16 + l16;
        Cf[(size_t)row * N + col] = acc[mt][nt][r];
      }
}

// ---------------- fused causal flash attention, S^T orientation ----------
// DUAL-STREAM PAIRED STRIPS + l-sum on MFMA pipe + FROZEN-MAX softmax (R9).
__device__ __forceinline__ void qk_dual(const u16* Ks, const half8* qfA, const half8* qfB,
                                        floatx4 (&sA)[8], floatx4 (&sB)[8],
                                        int quad, int l16) {
#pragma unroll
  for (int kc = 0; kc < 2; kc++)
#pragma unroll
    for (int st = 0; st < 8; st++) {
      int srow = st * 16 + l16;
      half8 ak = *(const half8*)&Ks[srow * 64 + (((kc * 4 + quad) ^ (srow & 7)) * 8)];
      sA[st] = __builtin_amdgcn_mfma_f32_16x16x32_f16(ak, qfA[kc], sA[st], 0, 0, 0);
      sB[st] = __builtin_amdgcn_mfma_f32_16x16x32_f16(ak, qfB[kc], sB[st], 0, 0, 0);
    }
}
__device__ __forceinline__ void qk_single(const u16* Ks, const half8* qfA,
                                          floatx4 (&sA)[8], int quad, int l16) {
#pragma unroll
  for (int kc = 0; kc < 2; kc++)
#pragma unroll
    for (int st = 0; st < 8; st++) {
      int srow = st * 16 + l16;
      half8 ak = *(const half8*)&Ks[srow * 64 + (((kc * 4 + quad) ^ (srow & 7)) * 8)];
      sA[st] = __builtin_amdgcn_mfma_f32_16x16x32_f16(ak, qfA[kc], sA[st], 0, 0, 0);
    }
}
__device__ __forceinline__ void apply_mask(floatx4 (&s)[8], int kt, int tw, int quad, int l16) {
  int tg = tw + l16;
#pragma unroll
  for (int st = 0; st < 8; st++) {
    int sg = kt * 128 + st * 16 + quad * 4;
#pragma unroll
    for (int r = 0; r < 4; r++)
      if (sg + r > tg) s[st][r] = -1e30f;
  }
}
__device__ __forceinline__ float vmax4(const floatx4& v) {
  return fmaxf(fmaxf(fmaxf(v[0], v[1]), v[2]), v[3]);
}
__device__ __forceinline__ float colmax(const floatx4 (&s)[8]) {
  float p0 = fmaxf(vmax4(s[0]), vmax4(s[1]));
  float p1 = fmaxf(vmax4(s[2]), vmax4(s[3]));
  float p2 = fmaxf(vmax4(s[4]), vmax4(s[5]));
  float p3 = fmaxf(vmax4(s[6]), vmax4(s[7]));
  float mx = fmaxf(fmaxf(p0, p1), fmaxf(p2, p3));
  mx = fmaxf(mx, __shfl_xor(mx, 16));
  mx = fmaxf(mx, __shfl_xor(mx, 32));
  return mx;
}
__device__ __forceinline__ void exp_sub(floatx4 (&s)[8], float m) {
#pragma unroll
  for (int st = 0; st < 8; st++)
#pragma unroll
    for (int r = 0; r < 4; r++) s[st][r] = exp2f(s[st][r] - m);
}
__device__ __forceinline__ void exp_ip(floatx4 (&s)[8]) {   // s already holds score-m
#pragma unroll
  for (int st = 0; st < 8; st++)
#pragma unroll
    for (int r = 0; r < 4; r++) s[st][r] = exp2f(s[st][r]);
}
__device__ __forceinline__ void pv_dual(const u16* Vts, const floatx4 (&sA)[8],
                                        const floatx4 (&sB)[8], floatx4 (&oA)[4],
                                        floatx4 (&oB)[4], floatx4& lsA, floatx4& lsB,
                                        int qh2, int ql2, int l16) {
  const half4 vones = {(_Float16)1.f, (_Float16)1.f, (_Float16)1.f, (_Float16)1.f};
#pragma unroll
  for (int st = 0; st < 8; st++) {
    union { unsigned u[2]; half4 h; } pa, pb;
    pa.u[0] = pk2h(sA[st][0], sA[st][1]); pa.u[1] = pk2h(sA[st][2], sA[st][3]);
    pb.u[0] = pk2h(sB[st][0], sB[st][1]); pb.u[1] = pk2h(sB[st][2], sB[st][3]);
    lsA = __builtin_amdgcn_mfma_f32_16x16x16f16(vones, pa.h, lsA, 0, 0, 0);
    lsB = __builtin_amdgcn_mfma_f32_16x16x16f16(vones, pb.h, lsB, 0, 0, 0);
#pragma unroll
    for (int dt = 0; dt < 4; dt++) {
      int drow = dt * 16 + l16;
      half4 av = *(const half4*)&Vts[drow * 128 + (((st * 2 + qh2) ^ (drow & 15)) * 8) + ql2];
      oA[dt] = __builtin_amdgcn_mfma_f32_16x16x16f16(av, pa.h, oA[dt], 0, 0, 0);
      oB[dt] = __builtin_amdgcn_mfma_f32_16x16x16f16(av, pb.h, oB[dt], 0, 0, 0);
    }
  }
}
__device__ __forceinline__ void pv_single(const u16* Vts, const floatx4 (&sA)[8],
                                          floatx4 (&oA)[4], floatx4& lsA,
                                          int qh2, int ql2, int l16) {
  const half4 vones = {(_Float16)1.f, (_Float16)1.f, (_Float16)1.f, (_Float16)1.f};
#pragma unroll
  for (int st = 0; st < 8; st++) {
    union { unsigned u[2]; half4 h; } pa;
    pa.u[0] = pk2h(sA[st][0], sA[st][1]); pa.u[1] = pk2h(sA[st][2], sA[st][3]);
    lsA = __builtin_amdgcn_mfma_f32_16x16x16f16(vones, pa.h, lsA, 0, 0, 0);
#pragma unroll
    for (int dt = 0; dt < 4; dt++) {
      int drow = dt * 16 + l16;
      half4 av = *(const half4*)&Vts[drow * 128 + (((st * 2 + qh2) ^ (drow & 15)) * 8) + ql2];
      oA[dt] = __builtin_amdgcn_mfma_f32_16x16x16f16(av, pa.h, oA[dt], 0, 0, 0);
    }
  }
}
__device__ __forceinline__ void epilogue(u16* __restrict__ Ob, const floatx4 (&oacc)[4],
                                         const floatx4& lsum, int b, int h, int tw,
                                         int quad, int l16) {
  int t = tw + l16;
  float invl = 1.f / lsum[0];               // all 4 regs identical (ones-rows)
#pragma unroll
  for (int dt = 0; dt < 4; dt++) {
    int d0 = dt * 16 + quad * 4;
    ushort4 o;
    o.x = f2bf(oacc[dt][0] * invl);
    o.y = f2bf(oacc[dt][1] * invl);
    o.z = f2bf(oacc[dt][2] * invl);
    o.w = f2bf(oacc[dt][3] * invl);
    *(ushort4*)&Ob[((size_t)(b * T_SEQ) + t) * CDIM + h * HD + d0] = o;
  }
}

__global__ __launch_bounds__(256, 2) void attn_fused(const u16* __restrict__ qf16,
                                                     const u16* __restrict__ kf16,
                                                     const u16* __restrict__ vtf,
                                                     u16* __restrict__ Ob) {
  __shared__ u16 Ks[128 * 64];              // K tile (s,d) f16, chunk-swizzled
  __shared__ u16 Vts[64 * 128];             // V^T tile (d,s) f16, chunk-swizzled
  const int tid = threadIdx.x;
  const int lane = tid & 63, wave = tid >> 6;
  const int quad = lane >> 4, l16 = lane & 15;
  const int qh2 = quad >> 1, ql2 = (quad & 1) * 4;
  const int j   = blockIdx.x >> 5;          // pair index 0..15
  const int bh  = blockIdx.x & 31;
  const int b = bh >> 4, h = bh & 15;

  const int qtA = 31 - j, qtB = j;          // heavy / light strip
  const int twA = qtA * 64 + wave * 16;
  const int twB = qtB * 64 + wave * 16;
  const int nktA = (qtA >> 1) + 1;          // 9..16 (holds A's diagonal)
  const int nktB = (qtB >> 1) + 1;          // 1..8  (strict prefix of A's range)

  const u16* QgA = qf16 + ((size_t)bh * T_SEQ + twA) * HD;
  const u16* QgB = qf16 + ((size_t)bh * T_SEQ + twB) * HD;
  half8 qfA[2], qfB[2];
#pragma unroll
  for (int kc = 0; kc < 2; kc++) {
    qfA[kc] = *(const half8*)&QgA[(size_t)l16 * HD + kc * 32 + quad * 8];
    qfB[kc] = *(const half8*)&QgB[(size_t)l16 * HD + kc * 32 + quad * 8];
  }

  floatx4 oaccA[4] = {}, oaccB[4] = {};
  floatx4 lsA = {}, lsB = {};
  float mA = 0.f, mB = 0.f;                 // frozen after tile 0

#pragma unroll 1
  for (int kt = 0; kt < nktA; kt++) {
    __syncthreads();
    const size_t koff = ((size_t)bh * T_SEQ + kt * 128) * HD;
    const u16* Vg = vtf + (size_t)bh * HD * T_SEQ + kt * 128;
#pragma unroll
    for (int jj = 0; jj < 4; jj++) {
      int t2 = jj * 256 + tid;
      int r = t2 >> 3, c = t2 & 7;
      gld16(kf16 + koff + r * HD + (c ^ (r & 7)) * 8, &Ks[t2 * 8]);
    }
#pragma unroll
    for (int jj = 0; jj < 4; jj++) {
      int t2 = jj * 256 + tid;
      int r = t2 >> 4, c = t2 & 15;
      gld16(Vg + (size_t)r * T_SEQ + (c ^ (r & 15)) * 8, &Vts[t2 * 8]);
    }
    __syncthreads();

    if (kt == 0) {
      // both streams' first tile: compute + freeze column max
      floatx4 sA[8] = {}, sB[8] = {};
      qk_dual(Ks, qfA, qfB, sA, sB, quad, l16);
      if (nktB == 1) apply_mask(sB, 0, twB, quad, l16);
      mA = colmax(sA); mB = colmax(sB);
      exp_sub(sA, mA); exp_sub(sB, mB);
      pv_dual(Vts, sA, sB, oaccA, oaccB, lsA, lsB, qh2, ql2, l16);
    } else if (kt < nktB) {
      // frozen max: sacc init to -m, QK MFMA's C-input does the subtract
      floatx4 sA[8], sB[8];
      floatx4 miA = {-mA, -mA, -mA, -mA}, miB = {-mB, -mB, -mB, -mB};
#pragma unroll
      for (int st = 0; st < 8; st++) { sA[st] = miA; sB[st] = miB; }
      qk_dual(Ks, qfA, qfB, sA, sB, quad, l16);
      if (kt == nktB - 1) apply_mask(sB, kt, twB, quad, l16);
      exp_ip(sA); exp_ip(sB);
      pv_dual(Vts, sA, sB, oaccA, oaccB, lsA, lsB, qh2, ql2, l16);
    } else {
      floatx4 sA[8];
      floatx4 miA = {-mA, -mA, -mA, -mA};
#pragma unroll
      for (int st = 0; st < 8; st++) sA[st] = miA;
      qk_single(Ks, qfA, sA, quad, l16);
      if (kt == nktA - 1) apply_mask(sA, kt, twA, quad, l16);
      exp_ip(sA);
      pv_single(Vts, sA, oaccA, lsA, qh2, ql2, l16);
    }
  }
  epilogue(Ob, oaccA, lsA, b, h, twA, quad, l16);
  epilogue(Ob, oaccB, lsB, b, h, twB, quad, l16);
}

extern "C" void kernel_launch(void* const* d_in, const int* in_sizes, int n_in,
                              void* d_out, int out_size, void* d_ws, size_t ws_size,
                              hipStream_t stream) {
  const float* x     = (const float*)d_in[0];
  const float* w_qkv = (const float*)d_in[2];
  const float* w_out = (const float*)d_in[3];
  float* out    = (float*)d_out;                       // (B,T,C) fp32
  float* kt_out = out + (size_t)BDIM * T_SEQ * CDIM;   // (B,H,T,64) fp32
  float* vt_out = kt_out + (size_t)BDIM * T_SEQ * CDIM;

  // workspace layout (48.5MB of 64MB)
  const size_t F = (size_t)4194304;     // 4M elems
  char* base = (char*)d_ws;
  u16* xb   = (u16*)base;                        // [0,8M)
  u16* wqT  = xb + F;                            // [8,14M)
  u16* woT  = wqT + (size_t)3145728;             // [14,16M)
  u16* qf16 = woT + (size_t)1048576;             // [16,24M)
  u16* kf16 = qf16 + F;                          // [24,32M)
  u16* vtf  = kf16 + F;                          // [32,40M)
  u16* Ob   = vtf + F;                           // [40,48M)
  float2* tab = (float2*)(base + (size_t)48 * 1024 * 1024);  // [48,48.5M)

  preproc<<<8448, 256, 0, stream>>>(x, w_qkv, w_out, xb, wqT, woT, tab);
  gemm_qkv_fused<<<dim3(32, 24), 256, 0, stream>>>(xb, wqT, tab, qf16, kf16, kt_out, vt_out, vtf);
  attn_fused<<<512, 256, 0, stream>>>(qf16, kf16, vtf, Ob);
  gemm_out<<<dim3(32, 16), 256, 0, stream>>>(Ob, woT, out);
}

// Round 16
// 191.955 us; speedup vs baseline: 1.0565x; 1.0565x over previous
//
#include <hip/hip_runtime.h>

// Problem constants (B=2, T=2048, C=1024, H=16, hd=64)
#define T_SEQ 2048
#define NH    16
#define HD    64
#define CDIM  1024
#define BDIM  2

using floatx4 = __attribute__((ext_vector_type(4))) float;
using bf16x8  = __attribute__((ext_vector_type(8))) __bf16;
using half4   = __attribute__((ext_vector_type(4))) _Float16;
using half8   = __attribute__((ext_vector_type(8))) _Float16;
typedef unsigned short u16;

__device__ __forceinline__ u16 f2bf(float f) {
  unsigned int u = __float_as_uint(f);
  u += 0x7fffu + ((u >> 16) & 1u);          // RNE
  return (u16)(u >> 16);
}
__device__ __forceinline__ float bf2f(u16 h) {
  return __uint_as_float(((unsigned int)h) << 16);
}
__device__ __forceinline__ u16 f2h(float f) {
  union { _Float16 h; u16 u; } c; c.h = (_Float16)f; return c.u;
}
// pack two f32 -> one u32 of 2 f16 (RNE, via scalar cvts; compiler fuses pack)
__device__ __forceinline__ unsigned pkh_rne(float a, float b) {
  return (unsigned)f2h(a) | ((unsigned)f2h(b) << 16);
}
// packed f32x2 -> f16x2 (RTZ)
__device__ __forceinline__ unsigned pk2h(float a, float b) {
  return __builtin_bit_cast(unsigned, __builtin_amdgcn_cvt_pkrtz(a, b));
}
// async global->LDS, 16B/lane; LDS dest must be wave-uniform base + lane*16.
__device__ __forceinline__ void gld16(const void* g, const void* l) {
  __builtin_amdgcn_global_load_lds(
      (const __attribute__((address_space(1))) unsigned int*)(unsigned long long)g,
      (__attribute__((address_space(3))) unsigned int*)(unsigned int)(unsigned long long)l,
      16, 0, 0);
}
// 2D XCD tiling: 8 XCDs = 4 row-groups x 2 col-groups (proven -5.7us in R8).
__device__ __forceinline__ void xcd_tile2d(int& row0, int& col0) {
  const int bid = blockIdx.y * gridDim.x + blockIdx.x;
  const int x = bid & 7, l = bid >> 3;
  const int rg = x >> 1, cg = x & 1;
  row0 = (rg * 8 + (l & 7)) * 128;
  col0 = (cg * (gridDim.y >> 1) + (l >> 3)) * 128;
}

// ---------------- fused preprocessing: x cast + weight transposes + trig table --------
// q/k sections of wqT get a per-head PAIR PERMUTATION: new row j holds old
// feature 2j (j<32) / 2(j-32)+1 (j>=32), making RoPE lane-local in the gemm
// epilogue. 2048x32 (t,i)->(cos,sin) table (512KB, L2-resident) replaces trig.
__global__ __launch_bounds__(256) void preproc(const float* __restrict__ x,
                                               const float* __restrict__ w_qkv,
                                               const float* __restrict__ w_out,
                                               u16* __restrict__ xb,
                                               u16* __restrict__ wqT,
                                               u16* __restrict__ woT,
                                               float2* __restrict__ tab) {
  __shared__ float tile[32][33];
  int blk = blockIdx.x, tid = threadIdx.x;
  if (blk >= 8192) {                        // trig table: 64K entries (t,i)
    int idx = (blk - 8192) * 256 + tid;
    int t = idx >> 5, i = idx & 31;
    float inv_rev = exp2f(-0.4152410118609203f * (float)i) * 0.15915494309189535f;
    float rev = (float)t * inv_rev;
    float fr  = rev - floorf(rev);
    tab[idx] = make_float2(__builtin_amdgcn_cosf(fr), __builtin_amdgcn_sinf(fr));
    return;
  }
  if (blk < 4096) {                         // cast x -> bf16 (4M floats, float4 per thread)
    int i = blk * 256 + tid;
    float4 v = ((const float4*)x)[i];
    ushort4 o;
    o.x = f2bf(v.x); o.y = f2bf(v.y); o.z = f2bf(v.z); o.w = f2bf(v.w);
    ((ushort4*)xb)[i] = o;
    return;
  }
  const float* W; u16* WT; int K, N, bx, by;
  if (blk < 4096 + 3072) {                  // w_qkv (1024,3072) -> wqT (3072,1024)
    int idx = blk - 4096; W = w_qkv; WT = wqT; K = 1024; N = 3072;
    bx = idx % 96; by = idx / 96;
  } else {                                  // w_out (1024,1024) -> woT
    int idx = blk - 7168; W = w_out; WT = woT; K = 1024; N = 1024;
    bx = idx & 31; by = idx >> 5;
  }
  int n0 = bx * 32, k0 = by * 32;
  int tx = tid & 31, ty = tid >> 5;         // (32,8)
#pragma unroll
  for (int i = 0; i < 32; i += 8)
    tile[ty + i][tx] = W[(size_t)(k0 + ty + i) * N + n0 + tx];
  __syncthreads();
#pragma unroll
  for (int i = 0; i < 32; i += 8) {
    int n = n0 + ty + i;
    int dest = n;
    if (N == 3072 && n < 2048) {            // q,k: pair-permute within each head
      int f = n & 63;
      dest = (n & ~63) | ((f >> 1) + ((f & 1) << 5));
    }
    WT[(size_t)dest * K + k0 + tx] = f2bf(tile[tx][ty + i]);
  }
}

// ---------------- QKV GEMM with fused RoPE + V-pack epilogue ----------
// PROVEN R10 mainloop — 2-phase dbuf + counted vmcnt(4) at 3 blocks/CU.
// Isolated A/Bs on this loop: single-buffer 48->70us (R11); 2-deep 3-buf
// prefetch 46->60us (R14: LDS 48KB + VGPR 96 cut occupancy 3->2 blocks/CU,
// killing m114 implicit wave overlap). In this 128^2-tile 2-barrier
// structure, occupancy beats pipeline depth — this form is the local optimum.
__global__ __launch_bounds__(256) void gemm_qkv_fused(const u16* __restrict__ A,
                                                      const u16* __restrict__ BT,
                                                      const float2* __restrict__ tab,
                                                      u16* __restrict__ qf16,
                                                      u16* __restrict__ kf16,
                                                      float* __restrict__ kt_out,
                                                      float* __restrict__ vt_out,
                                                      u16* __restrict__ vtf) {
  __shared__ u16 smem[4][128 * 32];         // [0..1]=A dbuf, [2..3]=B dbuf; reused for V^T
  const int K = 1024;
  const int tid  = threadIdx.x;
  const int lane = tid & 63, wave = tid >> 6;
  const int quad = lane >> 4, l16 = lane & 15;
  const int wm = (wave & 1) * 64, wn = (wave >> 1) * 64;
  int row0, col0;
  xcd_tile2d(row0, col0);
  const int srow = tid >> 2;
  const int sc   = tid & 3;
  const int sgc  = (sc ^ ((srow >> 1) & 3)) * 8;
  floatx4 acc[4][4] = {};

  auto stage = [&](int buf, int k0) {
    gld16(A  + (size_t)(row0 + srow     ) * K + k0 + sgc, &smem[buf][srow * 32 + sc * 8]);
    gld16(A  + (size_t)(row0 + srow + 64) * K + k0 + sgc, &smem[buf][(srow + 64) * 32 + sc * 8]);
    gld16(BT + (size_t)(col0 + srow     ) * K + k0 + sgc, &smem[2 + buf][srow * 32 + sc * 8]);
    gld16(BT + (size_t)(col0 + srow + 64) * K + k0 + sgc, &smem[2 + buf][(srow + 64) * 32 + sc * 8]);
  };

  const int nk = K >> 5;
  stage(0, 0);
  for (int ki = 0; ki < nk; ki++) {
    const int cur = ki & 1;
    __builtin_amdgcn_s_barrier();
    int kn = ki + 1 < nk ? ki + 1 : nk - 1;
    stage(cur ^ 1, kn << 5);
    asm volatile("s_waitcnt vmcnt(4)" ::: "memory");
    __builtin_amdgcn_s_barrier();
    bf16x8 af[4], bfv[4];
#pragma unroll
    for (int mt = 0; mt < 4; mt++) {
      int r = wm + mt * 16 + l16;
      af[mt] = *(const bf16x8*)&smem[cur][r * 32 + (quad ^ ((r >> 1) & 3)) * 8];
    }
#pragma unroll
    for (int nt = 0; nt < 4; nt++) {
      int r = wn + nt * 16 + l16;
      bfv[nt] = *(const bf16x8*)&smem[2 + cur][r * 32 + (quad ^ ((r >> 1) & 3)) * 8];
    }
#pragma unroll
    for (int mt = 0; mt < 4; mt++)
#pragma unroll
      for (int nt = 0; nt < 4; nt++)
        acc[mt][nt] = __builtin_amdgcn_mfma_f32_16x16x32_bf16(af[mt], bfv[nt], acc[mt][nt], 0, 0, 0);
  }
  asm volatile("s_waitcnt vmcnt(0)" ::: "memory");  // drain tail stage

  // ---- fused epilogue ----
  const int sec = col0 >> 10;               // 0=q, 1=k, 2=v
  const int h   = ((col0 & 1023) + wn) >> 6;  // wave's 64 cols = one head
  const int b   = row0 >> 11;               // whole block within one batch
  const int tbase = (row0 & 2047) + wm;     // wave's token base
  const size_t hb = (size_t)(b * NH + h) * T_SEQ;

  if (sec < 2) {
    // RoPE (lane-local): x1=acc[mt][no], x2=acc[mt][no+2]. d'-interleaved
    // store: one dword holds (o1(i), o2(i)) at u16 index rb + 2i.
    const float S = 0.18033688011112042f;   // 0.125 * log2(e): base-2 softmax
#pragma unroll
    for (int mt = 0; mt < 4; mt++)
#pragma unroll
      for (int r = 0; r < 4; r++) {
        int t = tbase + mt * 16 + quad * 4 + r;
        size_t rb = (hb + t) * 64;
#pragma unroll
        for (int no = 0; no < 2; no++) {
          int i = no * 16 + l16;
          float2 cn = tab[t * 32 + i];
          float x1 = acc[mt][no][r], x2 = acc[mt][no + 2][r];
          float o1 = x1 * cn.x - x2 * cn.y;
          float o2 = x1 * cn.y + x2 * cn.x;
          if (sec == 0) {
            *(unsigned*)&qf16[rb + 2 * i] = pkh_rne(o1 * S, o2 * S);
          } else {
            *(unsigned*)&kf16[rb + 2 * i] = pkh_rne(o1, o2);
            kt_out[rb + i]      = o1;       // canonical layout (checked output)
            kt_out[rb + i + 32] = o2;
          }
        }
      }
  } else {
    // V: vt_out fp32 direct (coalesced), vtf (BH,64,T) f16 via LDS transpose.
#pragma unroll
    for (int mt = 0; mt < 4; mt++)
#pragma unroll
      for (int nt = 0; nt < 4; nt++)
#pragma unroll
        for (int r = 0; r < 4; r++) {
          int t = tbase + mt * 16 + quad * 4 + r;
          vt_out[(hb + t) * 64 + nt * 16 + l16] = acc[mt][nt][r];
        }
    __syncthreads();                        // all waves done with staging LDS
    u16* tb = &smem[0][0] + wave * 2432;    // per-wave scratch (32 x stride-72)
#pragma unroll
    for (int p = 0; p < 2; p++) {           // two 32-d passes (fits LDS)
#pragma unroll
      for (int mt = 0; mt < 4; mt++)
#pragma unroll
        for (int ntl = 0; ntl < 2; ntl++) {
          int dl = ntl * 16 + l16;          // d within pass
          // pack 4 rows (r=0..3, consecutive rowr) into one ds_write_b64
          half4 hv;
          hv[0] = (_Float16)acc[mt][p * 2 + ntl][0];
          hv[1] = (_Float16)acc[mt][p * 2 + ntl][1];
          hv[2] = (_Float16)acc[mt][p * 2 + ntl][2];
          hv[3] = (_Float16)acc[mt][p * 2 + ntl][3];
          *(half4*)&tb[dl * 72 + mt * 16 + quad * 4] = hv;
        }
      // same-wave write->read on same pointer: compiler orders via lgkmcnt
#pragma unroll
      for (int it = 0; it < 8; it++) {
        int dl = it * 4 + quad;
        int d  = p * 32 + dl;
        ushort4 vv = *(const ushort4*)&tb[dl * 72 + l16 * 4];
        *(ushort4*)&vtf[((size_t)(b * NH + h) * 64 + d) * T_SEQ + tbase + l16 * 4] = vv;
      }
      __syncthreads();                      // pass isolation across waves sharing smem
    }
  }
}

// ---------------- output-projection GEMM: 128x64 tiles (proven R9) ----------
// Keeps dbuf + counted vmcnt: proven at low occupancy (R2, 1-2 blocks/CU).
__global__ __launch_bounds__(256) void gemm_out(const u16* __restrict__ A,
                                                const u16* __restrict__ BT,
                                                float* __restrict__ Cf) {
  __shared__ u16 As[2][128 * 32];
  __shared__ u16 Bs[2][64 * 32];
  const int K = 1024, N = 1024;
  const int tid  = threadIdx.x;
  const int lane = tid & 63, wave = tid >> 6;
  const int quad = lane >> 4, l16 = lane & 15;
  const int wm = (wave & 1) * 64, wn = (wave >> 1) * 32;
  const int bid = blockIdx.y * gridDim.x + blockIdx.x;   // grid (32,16)
  const int xx = bid & 7, l = bid >> 3;                  // l in 0..63
  const int row0 = ((xx >> 1) * 8 + (l & 7)) * 128;      // 32 row-tiles
  const int col0 = ((xx & 1) * 8 + (l >> 3)) * 64;       // 16 col-tiles (64 wide)
  const int srow = tid >> 2;
  const int sc   = tid & 3;
  const int sgc  = (sc ^ ((srow >> 1) & 3)) * 8;
  floatx4 acc[4][2] = {};

  auto stage = [&](int buf, int k0) {
    gld16(A  + (size_t)(row0 + srow     ) * K + k0 + sgc, &As[buf][srow * 32 + sc * 8]);
    gld16(A  + (size_t)(row0 + srow + 64) * K + k0 + sgc, &As[buf][(srow + 64) * 32 + sc * 8]);
    gld16(BT + (size_t)(col0 + srow     ) * K + k0 + sgc, &Bs[buf][srow * 32 + sc * 8]);
  };

  const int nk = K >> 5;
  stage(0, 0);
  for (int ki = 0; ki < nk; ki++) {
    const int cur = ki & 1;
    __builtin_amdgcn_s_barrier();
    int kn = ki + 1 < nk ? ki + 1 : nk - 1;
    stage(cur ^ 1, kn << 5);
    asm volatile("s_waitcnt vmcnt(3)" ::: "memory");  // tile ki landed; 3 in flight
    __builtin_amdgcn_s_barrier();
    bf16x8 af[4], bfv[2];
#pragma unroll
    for (int mt = 0; mt < 4; mt++) {
      int r = wm + mt * 16 + l16;
      af[mt] = *(const bf16x8*)&As[cur][r * 32 + (quad ^ ((r >> 1) & 3)) * 8];
    }
#pragma unroll
    for (int nt = 0; nt < 2; nt++) {
      int r = wn + nt * 16 + l16;
      bfv[nt] = *(const bf16x8*)&Bs[cur][r * 32 + (quad ^ ((r >> 1) & 3)) * 8];
    }
#pragma unroll
    for (int mt = 0; mt < 4; mt++)
#pragma unroll
      for (int nt = 0; nt < 2; nt++)
        acc[mt][nt] = __builtin_amdgcn_mfma_f32_16x16x32_bf16(af[mt], bfv[nt], acc[mt][nt], 0, 0, 0);
  }
  asm volatile("s_waitcnt vmcnt(0)" ::: "memory");
#pragma unroll
  for (int mt = 0; mt < 4; mt++)
#pragma unroll
    for (int nt = 0; nt < 2; nt++)
#pragma unroll
      for (int r = 0; r < 4; r++) {
        int row = row0 + wm + mt * 16 + quad * 4 + r;
        int col = col0 + wn + nt * 16 + l16;
        Cf[(size_t)row * N + col] = acc[mt][nt][r];
      }
}

// ---------------- fused causal flash attention, S^T orientation ----------
// DUAL-STREAM PAIRED STRIPS + l-sum on MFMA pipe + FROZEN-MAX softmax (R9).
__device__ __forceinline__ void qk_dual(const u16* Ks, const half8* qfA, const half8* qfB,
                                        floatx4 (&sA)[8], floatx4 (&sB)[8],
                                        int quad, int l16) {
#pragma unroll
  for (int kc = 0; kc < 2; kc++)
#pragma unroll
    for (int st = 0; st < 8; st++) {
      int srow = st * 16 + l16;
      half8 ak = *(const half8*)&Ks[srow * 64 + (((kc * 4 + quad) ^ (srow & 7)) * 8)];
      sA[st] = __builtin_amdgcn_mfma_f32_16x16x32_f16(ak, qfA[kc], sA[st], 0, 0, 0);
      sB[st] = __builtin_amdgcn_mfma_f32_16x16x32_f16(ak, qfB[kc], sB[st], 0, 0, 0);
    }
}
__device__ __forceinline__ void qk_single(const u16* Ks, const half8* qfA,
                                          floatx4 (&sA)[8], int quad, int l16) {
#pragma unroll
  for (int kc = 0; kc < 2; kc++)
#pragma unroll
    for (int st = 0; st < 8; st++) {
      int srow = st * 16 + l16;
      half8 ak = *(const half8*)&Ks[srow * 64 + (((kc * 4 + quad) ^ (srow & 7)) * 8)];
      sA[st] = __builtin_amdgcn_mfma_f32_16x16x32_f16(ak, qfA[kc], sA[st], 0, 0, 0);
    }
}
__device__ __forceinline__ void apply_mask(floatx4 (&s)[8], int kt, int tw, int quad, int l16) {
  int tg = tw + l16;
#pragma unroll
  for (int st = 0; st < 8; st++) {
    int sg = kt * 128 + st * 16 + quad * 4;
#pragma unroll
    for (int r = 0; r < 4; r++)
      if (sg + r > tg) s[st][r] = -1e30f;
  }
}
__device__ __forceinline__ float vmax4(const floatx4& v) {
  return fmaxf(fmaxf(fmaxf(v[0], v[1]), v[2]), v[3]);
}
__device__ __forceinline__ float colmax(const floatx4 (&s)[8]) {
  float p0 = fmaxf(vmax4(s[0]), vmax4(s[1]));
  float p1 = fmaxf(vmax4(s[2]), vmax4(s[3]));
  float p2 = fmaxf(vmax4(s[4]), vmax4(s[5]));
  float p3 = fmaxf(vmax4(s[6]), vmax4(s[7]));
  float mx = fmaxf(fmaxf(p0, p1), fmaxf(p2, p3));
  mx = fmaxf(mx, __shfl_xor(mx, 16));
  mx = fmaxf(mx, __shfl_xor(mx, 32));
  return mx;
}
__device__ __forceinline__ void exp_sub(floatx4 (&s)[8], float m) {
#pragma unroll
  for (int st = 0; st < 8; st++)
#pragma unroll
    for (int r = 0; r < 4; r++) s[st][r] = exp2f(s[st][r] - m);
}
__device__ __forceinline__ void exp_ip(floatx4 (&s)[8]) {   // s already holds score-m
#pragma unroll
  for (int st = 0; st < 8; st++)
#pragma unroll
    for (int r = 0; r < 4; r++) s[st][r] = exp2f(s[st][r]);
}
__device__ __forceinline__ void pv_dual(const u16* Vts, const floatx4 (&sA)[8],
                                        const floatx4 (&sB)[8], floatx4 (&oA)[4],
                                        floatx4 (&oB)[4], floatx4& lsA, floatx4& lsB,
                                        int qh2, int ql2, int l16) {
  const half4 vones = {(_Float16)1.f, (_Float16)1.f, (_Float16)1.f, (_Float16)1.f};
#pragma unroll
  for (int st = 0; st < 8; st++) {
    union { unsigned u[2]; half4 h; } pa, pb;
    pa.u[0] = pk2h(sA[st][0], sA[st][1]); pa.u[1] = pk2h(sA[st][2], sA[st][3]);
    pb.u[0] = pk2h(sB[st][0], sB[st][1]); pb.u[1] = pk2h(sB[st][2], sB[st][3]);
    lsA = __builtin_amdgcn_mfma_f32_16x16x16f16(vones, pa.h, lsA, 0, 0, 0);
    lsB = __builtin_amdgcn_mfma_f32_16x16x16f16(vones, pb.h, lsB, 0, 0, 0);
#pragma unroll
    for (int dt = 0; dt < 4; dt++) {
      int drow = dt * 16 + l16;
      half4 av = *(const half4*)&Vts[drow * 128 + (((st * 2 + qh2) ^ (drow & 15)) * 8) + ql2];
      oA[dt] = __builtin_amdgcn_mfma_f32_16x16x16f16(av, pa.h, oA[dt], 0, 0, 0);
      oB[dt] = __builtin_amdgcn_mfma_f32_16x16x16f16(av, pb.h, oB[dt], 0, 0, 0);
    }
  }
}
__device__ __forceinline__ void pv_single(const u16* Vts, const floatx4 (&sA)[8],
                                          floatx4 (&oA)[4], floatx4& lsA,
                                          int qh2, int ql2, int l16) {
  const half4 vones = {(_Float16)1.f, (_Float16)1.f, (_Float16)1.f, (_Float16)1.f};
#pragma unroll
  for (int st = 0; st < 8; st++) {
    union { unsigned u[2]; half4 h; } pa;
    pa.u[0] = pk2h(sA[st][0], sA[st][1]); pa.u[1] = pk2h(sA[st][2], sA[st][3]);
    lsA = __builtin_amdgcn_mfma_f32_16x16x16f16(vones, pa.h, lsA, 0, 0, 0);
#pragma unroll
    for (int dt = 0; dt < 4; dt++) {
      int drow = dt * 16 + l16;
      half4 av = *(const half4*)&Vts[drow * 128 + (((st * 2 + qh2) ^ (drow & 15)) * 8) + ql2];
      oA[dt] = __builtin_amdgcn_mfma_f32_16x16x16f16(av, pa.h, oA[dt], 0, 0, 0);
    }
  }
}
__device__ __forceinline__ void epilogue(u16* __restrict__ Ob, const floatx4 (&oacc)[4],
                                         const floatx4& lsum, int b, int h, int tw,
                                         int quad, int l16) {
  int t = tw + l16;
  float invl = 1.f / lsum[0];               // all 4 regs identical (ones-rows)
#pragma unroll
  for (int dt = 0; dt < 4; dt++) {
    int d0 = dt * 16 + quad * 4;
    ushort4 o;
    o.x = f2bf(oacc[dt][0] * invl);
    o.y = f2bf(oacc[dt][1] * invl);
    o.z = f2bf(oacc[dt][2] * invl);
    o.w = f2bf(oacc[dt][3] * invl);
    *(ushort4*)&Ob[((size_t)(b * T_SEQ) + t) * CDIM + h * HD + d0] = o;
  }
}

__global__ __launch_bounds__(256, 2) void attn_fused(const u16* __restrict__ qf16,
                                                     const u16* __restrict__ kf16,
                                                     const u16* __restrict__ vtf,
                                                     u16* __restrict__ Ob) {
  __shared__ u16 Ks[128 * 64];              // K tile (s,d) f16, chunk-swizzled
  __shared__ u16 Vts[64 * 128];             // V^T tile (d,s) f16, chunk-swizzled
  const int tid = threadIdx.x;
  const int lane = tid & 63, wave = tid >> 6;
  const int quad = lane >> 4, l16 = lane & 15;
  const int qh2 = quad >> 1, ql2 = (quad & 1) * 4;
  const int j   = blockIdx.x >> 5;          // pair index 0..15
  const int bh  = blockIdx.x & 31;
  const int b = bh >> 4, h = bh & 15;

  const int qtA = 31 - j, qtB = j;          // heavy / light strip
  const int twA = qtA * 64 + wave * 16;
  const int twB = qtB * 64 + wave * 16;
  const int nktA = (qtA >> 1) + 1;          // 9..16 (holds A's diagonal)
  const int nktB = (qtB >> 1) + 1;          // 1..8  (strict prefix of A's range)

  const u16* QgA = qf16 + ((size_t)bh * T_SEQ + twA) * HD;
  const u16* QgB = qf16 + ((size_t)bh * T_SEQ + twB) * HD;
  half8 qfA[2], qfB[2];
#pragma unroll
  for (int kc = 0; kc < 2; kc++) {
    qfA[kc] = *(const half8*)&QgA[(size_t)l16 * HD + kc * 32 + quad * 8];
    qfB[kc] = *(const half8*)&QgB[(size_t)l16 * HD + kc * 32 + quad * 8];
  }

  floatx4 oaccA[4] = {}, oaccB[4] = {};
  floatx4 lsA = {}, lsB = {};
  float mA = 0.f, mB = 0.f;                 // frozen after tile 0

#pragma unroll 1
  for (int kt = 0; kt < nktA; kt++) {
    __syncthreads();
    const size_t koff = ((size_t)bh * T_SEQ + kt * 128) * HD;
    const u16* Vg = vtf + (size_t)bh * HD * T_SEQ + kt * 128;
#pragma unroll
    for (int jj = 0; jj < 4; jj++) {
      int t2 = jj * 256 + tid;
      int r = t2 >> 3, c = t2 & 7;
      gld16(kf16 + koff + r * HD + (c ^ (r & 7)) * 8, &Ks[t2 * 8]);
    }
#pragma unroll
    for (int jj = 0; jj < 4; jj++) {
      int t2 = jj * 256 + tid;
      int r = t2 >> 4, c = t2 & 15;
      gld16(Vg + (size_t)r * T_SEQ + (c ^ (r & 15)) * 8, &Vts[t2 * 8]);
    }
    __syncthreads();

    if (kt == 0) {
      // both streams' first tile: compute + freeze column max
      floatx4 sA[8] = {}, sB[8] = {};
      qk_dual(Ks, qfA, qfB, sA, sB, quad, l16);
      if (nktB == 1) apply_mask(sB, 0, twB, quad, l16);
      mA = colmax(sA); mB = colmax(sB);
      exp_sub(sA, mA); exp_sub(sB, mB);
      pv_dual(Vts, sA, sB, oaccA, oaccB, lsA, lsB, qh2, ql2, l16);
    } else if (kt < nktB) {
      // frozen max: sacc init to -m, QK MFMA's C-input does the subtract
      floatx4 sA[8], sB[8];
      floatx4 miA = {-mA, -mA, -mA, -mA}, miB = {-mB, -mB, -mB, -mB};
#pragma unroll
      for (int st = 0; st < 8; st++) { sA[st] = miA; sB[st] = miB; }
      qk_dual(Ks, qfA, qfB, sA, sB, quad, l16);
      if (kt == nktB - 1) apply_mask(sB, kt, twB, quad, l16);
      exp_ip(sA); exp_ip(sB);
      pv_dual(Vts, sA, sB, oaccA, oaccB, lsA, lsB, qh2, ql2, l16);
    } else {
      floatx4 sA[8];
      floatx4 miA = {-mA, -mA, -mA, -mA};
#pragma unroll
      for (int st = 0; st < 8; st++) sA[st] = miA;
      qk_single(Ks, qfA, sA, quad, l16);
      if (kt == nktA - 1) apply_mask(sA, kt, twA, quad, l16);
      exp_ip(sA);
      pv_single(Vts, sA, oaccA, lsA, qh2, ql2, l16);
    }
  }
  epilogue(Ob, oaccA, lsA, b, h, twA, quad, l16);
  epilogue(Ob, oaccB, lsB, b, h, twB, quad, l16);
}

extern "C" void kernel_launch(void* const* d_in, const int* in_sizes, int n_in,
                              void* d_out, int out_size, void* d_ws, size_t ws_size,
                              hipStream_t stream) {
  const float* x     = (const float*)d_in[0];
  const float* w_qkv = (const float*)d_in[2];
  const float* w_out = (const float*)d_in[3];
  float* out    = (float*)d_out;                       // (B,T,C) fp32
  float* kt_out = out + (size_t)BDIM * T_SEQ * CDIM;   // (B,H,T,64) fp32
  float* vt_out = kt_out + (size_t)BDIM * T_SEQ * CDIM;

  // workspace layout (48.5MB of 64MB)
  const size_t F = (size_t)4194304;     // 4M elems
  char* base = (char*)d_ws;
  u16* xb   = (u16*)base;                        // [0,8M)
  u16* wqT  = xb + F;                            // [8,14M)
  u16* woT  = wqT + (size_t)3145728;             // [14,16M)
  u16* qf16 = woT + (size_t)1048576;             // [16,24M)
  u16* kf16 = qf16 + F;                          // [24,32M)
  u16* vtf  = kf16 + F;                          // [32,40M)
  u16* Ob   = vtf + F;                           // [40,48M)
  float2* tab = (float2*)(base + (size_t)48 * 1024 * 1024);  // [48,48.5M)

  preproc<<<8448, 256, 0, stream>>>(x, w_qkv, w_out, xb, wqT, woT, tab);
  gemm_qkv_fused<<<dim3(32, 24), 256, 0, stream>>>(xb, wqT, tab, qf16, kf16, kt_out, vt_out, vtf);
  attn_fused<<<512, 256, 0, stream>>>(qf16, kf16, vtf, Ob);
  gemm_out<<<dim3(32, 16), 256, 0, stream>>>(Ob, woT, out);
}